// Round 7
// baseline (493.649 us; speedup 1.0000x reference)
//
#include <hip/hip_runtime.h>
#include <cstdint>

// MultiHeadAttention: B=2 S=2048 D=768 H=12 dk=64, fp32 in/out, bf16 MFMA inside.
//
//   convert : w_q,w_k,w_v,w_o fp32 -> bf16                        (ws)
//   qkv     : z=0 Qh[b][h][s][64] = (q @ w_q^T + b_q)*(log2e/8)   (bf16, ws)
//             z=1 Kh[b][h][s][64] =  k @ w_k^T + b_k              (bf16, ws)
//             z=2 Vt[b][h][64][t] = (v @ w_v^T + b_v)^T           (bf16, ws)
//             64x128 tiles, depth-2 prefetch (issued AFTER the barrier so the
//             compiler's vmcnt(0)-before-s_barrier drain waits on loads issued
//             a full iteration earlier), XCD-swizzled grid (1152 blocks)
//   attn    : ctx[tok][768]   = flash attention (no-max softmax)  (bf16, ws)
//   oproj   : out[tok][768]   = ctx @ w_o^T + b_o  (384 blocks)   (fp32, d_out)

#define S_LEN 2048
#define NHEAD 12
#define DMODEL 768

typedef short s16x8 __attribute__((ext_vector_type(8)));
typedef float f32x4 __attribute__((ext_vector_type(4)));

#define MFMA16(a, b, c) __builtin_amdgcn_mfma_f32_16x16x32_bf16((a), (b), (c), 0, 0, 0)

__device__ __forceinline__ unsigned int pk_bf16(float a, float b) {
  unsigned int ua = __float_as_uint(a), ub = __float_as_uint(b);
  ua = (ua + 0x7FFFu + ((ua >> 16) & 1u)) >> 16;   // RNE
  ub = (ub + 0x7FFFu + ((ub >> 16) & 1u)) >> 16;
  return ua | (ub << 16);
}
__device__ __forceinline__ short bf16r(float a) {
  unsigned int ua = __float_as_uint(a);
  return (short)((ua + 0x7FFFu + ((ua >> 16) & 1u)) >> 16);
}
// pack hi16(b)<<16 | hi16(a) in ONE v_perm_b32 (trunc; bias cancelled via l)
__device__ __forceinline__ unsigned int pk_trunc(float a, float b) {
  return __builtin_amdgcn_perm(__float_as_uint(b), __float_as_uint(a), 0x07060302u);
}
__device__ __forceinline__ float bf16_floor(float a) {
  return __uint_as_float(__float_as_uint(a) & 0xFFFF0000u);
}

// ---------------------------------------------------------------------------
// Weight fp32 -> bf16 convert. grid (576, 4) x 256 threads, float4/thread.
// ---------------------------------------------------------------------------
__global__ __launch_bounds__(256)
void convert_w(const float* __restrict__ w0, const float* __restrict__ w1,
               const float* __restrict__ w2, const float* __restrict__ w3,
               short* __restrict__ o0, short* __restrict__ o1,
               short* __restrict__ o2, short* __restrict__ o3) {
  const float* src = (blockIdx.y == 0) ? w0 : (blockIdx.y == 1) ? w1
                   : (blockIdx.y == 2) ? w2 : w3;
  short* dst = (blockIdx.y == 0) ? o0 : (blockIdx.y == 1) ? o1
             : (blockIdx.y == 2) ? o2 : o3;
  const long i = ((long)blockIdx.x * 256 + threadIdx.x) * 4;
  float4 f = *(const float4*)(src + i);
  uint2 u;
  u.x = pk_bf16(f.x, f.y);
  u.y = pk_bf16(f.z, f.w);
  *(uint2*)(dst + i) = u;
}

// ---------------------------------------------------------------------------
// 64x128 GEMM body, depth-2 register prefetch, double-buffered LDS, one
// barrier per K-iter. C[m][n] = sum_k A[m][k]*B[n][k], K=768, BK=32.
// Schedule (iter i, cur=i&1):
//   barrier            -> buf[cur] visible; drains fetch issued at iter i-1
//   fetch(set cur, tile i+2)            (after barrier: ~1-iter flight time)
//   compute buf[cur] (tile i)
//   store(set cur^1 -> buf[cur^1])      (tile i+1; data already drained)
// LDS: A 2x64x40 + B 2x128x40 shorts = 30 KB -> 5 blocks/CU.
// ---------------------------------------------------------------------------
template <bool ABF>
__device__ __forceinline__ void gemm64x128db(const void* __restrict__ Av,
                                             const short* __restrict__ Bv,
                                             int m0, int n0, f32x4 (&acc)[2][4],
                                             short* Alds, short* Blds) {
  constexpr int K = 768;
  constexpr int NIT = K / 32;          // 24
  const int tid  = threadIdx.x;
  const int lane = tid & 63;
  const int w    = tid >> 6;
  const int g    = lane >> 4;
  const int c    = lane & 15;
  const int wm   = (w & 1) * 32;
  const int wn   = (w >> 1) * 64;
  const int ar   = tid >> 2, ac = (tid & 3) * 8;    // A 64x32: 8 shorts/thr
  const int br   = tid >> 1, bc = (tid & 1) * 16;   // B 128x32: 16 shorts/thr

#pragma unroll
  for (int i = 0; i < 2; ++i)
#pragma unroll
    for (int j = 0; j < 4; ++j) acc[i][j] = (f32x4){0.f, 0.f, 0.f, 0.f};

  float4 raf[2][2];   // fp32 A path, 2 sets
  uint4  rab[2];      // bf16 A path
  uint4  rb[2][2];

  auto fetch = [&](int set, int kt) {
    if (ABF) {
      rab[set] = *(const uint4*)((const short*)Av + (long)(m0 + ar) * K + kt + ac);
    } else {
      const float* Ap = (const float*)Av + (long)(m0 + ar) * K + kt + ac;
      raf[set][0] = ((const float4*)Ap)[0];
      raf[set][1] = ((const float4*)Ap)[1];
    }
    const short* Bp = Bv + (long)(n0 + br) * K + kt + bc;
    rb[set][0] = *(const uint4*)Bp;
    rb[set][1] = *(const uint4*)(Bp + 8);
  };
  auto store = [&](int set, int buf) {
    short* Ab = Alds + buf * (64 * 40);
    short* Bb = Blds + buf * (128 * 40);
    if (ABF) {
      *(uint4*)&Ab[ar * 40 + ac] = rab[set];
    } else {
      uint4 u;
      u.x = pk_bf16(raf[set][0].x, raf[set][0].y);
      u.y = pk_bf16(raf[set][0].z, raf[set][0].w);
      u.z = pk_bf16(raf[set][1].x, raf[set][1].y);
      u.w = pk_bf16(raf[set][1].z, raf[set][1].w);
      *(uint4*)&Ab[ar * 40 + ac] = u;
    }
    *(uint4*)&Bb[br * 40 + bc]     = rb[set][0];
    *(uint4*)&Bb[br * 40 + bc + 8] = rb[set][1];
  };

  fetch(0, 0);        // tile 0 -> set 0
  fetch(1, 32);       // tile 1 -> set 1 (in flight while tile 0 stores)
  store(0, 0);        // buf0 = tile 0
  for (int it = 0; it < NIT; ++it) {
    const int cur = it & 1;
    __syncthreads();         // buf[cur] visible; drains iter i-1's fetch
    const int kt2 = (it + 2 < NIT) ? (it + 2) * 32 : 0;
    fetch(cur, kt2);         // tile it+2 -> set cur (consumed next iter's store)

    const short* Ab = Alds + cur * (64 * 40);
    const short* Bb = Blds + cur * (128 * 40);
    s16x8 af[2], bf[4];
#pragma unroll
    for (int mb = 0; mb < 2; ++mb)
      af[mb] = *(const s16x8*)&Ab[(wm + mb * 16 + c) * 40 + g * 8];
#pragma unroll
    for (int nb = 0; nb < 4; ++nb)
      bf[nb] = *(const s16x8*)&Bb[(wn + nb * 16 + c) * 40 + g * 8];
#pragma unroll
    for (int mb = 0; mb < 2; ++mb)
#pragma unroll
      for (int nb = 0; nb < 4; ++nb)
        acc[mb][nb] = MFMA16(af[mb], bf[nb], acc[mb][nb]);

    store(cur ^ 1, cur ^ 1); // tile it+1 -> buf[(it+1)&1]
  }
}

// ---------------------------------------------------------------------------
// Fused QKV projection. 1152 blocks, XCD-swizzled: xcd = L&7 owns whole
// (m,z) A-tiles; the 6 n-siblings of an A-tile are consecutive on that XCD.
// ---------------------------------------------------------------------------
__global__ __launch_bounds__(256)
void qkv_kernel(const float* __restrict__ q, const float* __restrict__ k,
                const float* __restrict__ v,
                const short* __restrict__ wq, const short* __restrict__ wk,
                const short* __restrict__ wv,
                const float* __restrict__ bq, const float* __restrict__ bk,
                const float* __restrict__ bv,
                short* __restrict__ qh, short* __restrict__ kh,
                short* __restrict__ vt) {
  __shared__ short Alds[2 * 64 * 40];
  __shared__ short Blds[2 * 128 * 40];

  const int L   = blockIdx.x;        // 0..1151
  const int xcd = L & 7;
  const int i   = L >> 3;            // 0..143
  const int nt  = i % 6;
  const int pl  = xcd * 24 + i / 6;  // 0..191 (m,z) pair
  const int z   = pl >> 6;
  const int mt  = pl & 63;
  const int m0  = mt * 64;           // token
  const int n0  = nt * 128;          // feature

  const float* A = (z == 0) ? q : (z == 1) ? k : v;
  const short* B = (z == 0) ? wq : (z == 1) ? wk : wv;
  const float* bias = (z == 0) ? bq : (z == 1) ? bk : bv;

  f32x4 acc[2][4];
  gemm64x128db<false>(A, B, m0, n0, acc, Alds, Blds);

  const int lane = threadIdx.x & 63, w = threadIdx.x >> 6;
  const int g = lane >> 4, c = lane & 15;
  const int wm = (w & 1) * 32, wn = (w >> 1) * 64;

  if (z < 2) {
    short* outp = z ? kh : qh;
    const float scale = z ? 1.0f : 0.18033688011112042f;  // log2e/8
#pragma unroll
    for (int mb = 0; mb < 2; ++mb) {
#pragma unroll
      for (int nb = 0; nb < 4; ++nb) {
        const int n = n0 + wn + nb * 16 + c;
        const float bvv = bias[n];
        const int hh = n >> 6, d = n & 63;
#pragma unroll
        for (int r = 0; r < 4; ++r) {
          const int m = m0 + wm + mb * 16 + g * 4 + r;
          const int b = m >> 11, s = m & 2047;
          const float val = (acc[mb][nb][r] + bvv) * scale;
          outp[(((long)(b * NHEAD + hh) * S_LEN + s) << 6) + d] = bf16r(val);
        }
      }
    }
  } else {  // V: transposed write Vt[b][h][d][t], 4 consecutive t per lane
#pragma unroll
    for (int mb = 0; mb < 2; ++mb) {
#pragma unroll
      for (int nb = 0; nb < 4; ++nb) {
        const int n = n0 + wn + nb * 16 + c;   // feature
        const float bvv = bias[n];
        const int hh = n >> 6, d = n & 63;
        const int m_base = m0 + wm + mb * 16 + g * 4;   // token base
        const int b = m_base >> 11, t = m_base & 2047;
        uint2 ov;
        ov.x = pk_bf16(acc[mb][nb][0] + bvv, acc[mb][nb][1] + bvv);
        ov.y = pk_bf16(acc[mb][nb][2] + bvv, acc[mb][nb][3] + bvv);
        *(uint2*)(vt + ((long)(b * NHEAD + hh) * 64 + d) * S_LEN + t) = ov;
      }
    }
  }
}

// ---------------------------------------------------------------------------
// Output projection. A = ctx (bf16), B = w_o (bf16), out fp32.
// 384 blocks, XCD-swizzled: xcd owns 8 m-tiles (6 n-siblings consecutive).
// ---------------------------------------------------------------------------
__global__ __launch_bounds__(256)
void o_kernel(const short* __restrict__ ctx, const short* __restrict__ wo,
              const float* __restrict__ bo, float* __restrict__ out) {
  __shared__ short Alds[2 * 64 * 40];
  __shared__ short Blds[2 * 128 * 40];

  const int L   = blockIdx.x;        // 0..383
  const int xcd = L & 7;
  const int i   = L >> 3;            // 0..47
  const int nt  = i % 6;
  const int mt  = xcd * 8 + i / 6;   // 0..63
  const int m0  = mt * 64;
  const int n0  = nt * 128;

  f32x4 acc[2][4];
  gemm64x128db<true>(ctx, wo, m0, n0, acc, Alds, Blds);

  const int lane = threadIdx.x & 63, w = threadIdx.x >> 6;
  const int g = lane >> 4, c = lane & 15;
  const int wm = (w & 1) * 32, wn = (w >> 1) * 64;
#pragma unroll
  for (int mb = 0; mb < 2; ++mb) {
#pragma unroll
    for (int nb = 0; nb < 4; ++nb) {
      const int n = n0 + wn + nb * 16 + c;
      const float bvv = bo[n];
#pragma unroll
      for (int r = 0; r < 4; ++r) {
        const int m = m0 + wm + mb * 16 + g * 4 + r;
        out[(long)m * DMODEL + n] = acc[mb][nb][r] + bvv;
      }
    }
  }
}

// ---------------------------------------------------------------------------
// Flash attention, no-max softmax. Depth-2 K/V prefetch (fetch issued AFTER
// the barrier), double-buffered kbuf/vbuf, one barrier/iter.
// fetchKV(set, t0): t0 = starting ROW of the K tile (= starting t-col of Vt),
// i.e. tile*64. (Round-6 bug: passed tile index here.)
// pbuf: stride 64 + 16B-granule XOR swizzle; LDS total 40960 B = 4 blocks/CU.
// ---------------------------------------------------------------------------
__global__ __launch_bounds__(256)
void attn_kernel(const short* __restrict__ Qh, const short* __restrict__ Kh,
                 const short* __restrict__ Vt, short* __restrict__ Ctx) {
  __shared__ short kbuf[2][64 * 64];      // swizzled [t][d]
  __shared__ short vbuf[2][64 * 64];      // swizzled [d][t]
  __shared__ short pbuf[4][16 * 64];      // per-wave [s][t], XOR-swizzled

  const int tid  = threadIdx.x;
  const int lane = tid & 63;
  const int w    = tid >> 6;
  const int g    = lane >> 4;
  const int c    = lane & 15;
  const int bh   = blockIdx.y;            // 0..23
  const int qs0  = blockIdx.x * 64;
  const long base = (long)bh * S_LEN * 64;
  const short* Qb = Qh + base;
  const short* Kb = Kh + base;
  const short* Vb = Vt + base;

  // Q fragments (B operand): n=s=lane&15, k=d=quad*8+j (+32*kb)
  const long qrow = (long)(qs0 + w * 16 + c) * 64;
  const s16x8 qf0 = *(const s16x8*)(Qb + qrow + g * 8);
  const s16x8 qf1 = *(const s16x8*)(Qb + qrow + 32 + g * 8);

  f32x4 co[4];
#pragma unroll
  for (int i = 0; i < 4; ++i) co[i] = (f32x4){0.f, 0.f, 0.f, 0.f};
  float l_lane = 0.f;

  const int srow = tid >> 2;           // 0..63
  const int sq   = tid & 3;
  const int sw   = srow & 7;
  const int sg0  = ((2 * sq)     ^ sw) * 8;
  const int sg1  = ((2 * sq + 1) ^ sw) * 8;
  const int cw   = c & 7;
  const int rg0  = ((g)     ^ cw) * 8;
  const int rg1  = ((4 + g) ^ cw) * 8;

  const short* kg = Kb + (long)srow * 64 + sq * 16;     // + row*64
  const short* vg = Vb + (long)srow * S_LEN + sq * 16;  // + t

  uint4 rk[2][2], rv[2][2];
  auto fetchKV = [&](int set, long t0) {   // t0 = starting row/t (tile*64)
    rk[set][0] = *(const uint4*)(kg + t0 * 64);
    rk[set][1] = *(const uint4*)(kg + t0 * 64 + 8);
    rv[set][0] = *(const uint4*)(vg + t0);
    rv[set][1] = *(const uint4*)(vg + t0 + 8);
  };
  auto storeKV = [&](int set, int buf) {
    *(uint4*)&kbuf[buf][srow * 64 + sg0] = rk[set][0];
    *(uint4*)&kbuf[buf][srow * 64 + sg1] = rk[set][1];
    *(uint4*)&vbuf[buf][srow * 64 + sg0] = rv[set][0];
    *(uint4*)&vbuf[buf][srow * 64 + sg1] = rv[set][1];
  };

  fetchKV(0, 0);          // tile 0 -> set 0
  fetchKV(1, 64);         // tile 1 -> set 1 (in flight while tile 0 stores)
  storeKV(0, 0);          // buf0 = tile 0

  // pbuf swizzled offsets (stride 64 shorts, 16B granules XOR (c&7))
  const int pr0 = c * 64 + ((g ^ cw) * 8);
  const int pr1 = c * 64 + (((4 + g) ^ cw) * 8);

  for (int it = 0; it < S_LEN / 64; ++it) {
    const int cur = it & 1;
    __syncthreads();       // buf[cur] visible; drains iter i-1's fetch
    const long tn = (it + 2 < S_LEN / 64) ? (long)(it + 2) * 64 : 0;
    fetchKV(cur, tn);      // tile it+2 -> set cur

    // S^T[t][s]: A = K (m=t), B = Q (n=s)
    f32x4 st[4];
#pragma unroll
    for (int mb = 0; mb < 4; ++mb) {
      const s16x8 k0 = *(const s16x8*)&kbuf[cur][(mb * 16 + c) * 64 + rg0];
      const s16x8 k1 = *(const s16x8*)&kbuf[cur][(mb * 16 + c) * 64 + rg1];
      f32x4 z = (f32x4){0.f, 0.f, 0.f, 0.f};
      z = MFMA16(k0, qf0, z);
      z = MFMA16(k1, qf1, z);
      st[mb] = z;
    }

    // P = exp2(S'); l from TRUNCATED values; pack via v_perm
#pragma unroll
    for (int mb = 0; mb < 4; ++mb) {
      float p0 = __builtin_amdgcn_exp2f(st[mb][0]);
      float p1 = __builtin_amdgcn_exp2f(st[mb][1]);
      float p2 = __builtin_amdgcn_exp2f(st[mb][2]);
      float p3 = __builtin_amdgcn_exp2f(st[mb][3]);
      l_lane += bf16_floor(p0) + bf16_floor(p1) + bf16_floor(p2) + bf16_floor(p3);
      uint2 pw;
      pw.x = pk_trunc(p0, p1);
      pw.y = pk_trunc(p2, p3);
      const int pg = ((2 * mb + (g >> 1)) ^ cw) * 8 + (g & 1) * 4;
      *(uint2*)&pbuf[w][c * 64 + pg] = pw;
    }
    const s16x8 pb0 = *(const s16x8*)&pbuf[w][pr0];
    const s16x8 pb1 = *(const s16x8*)&pbuf[w][pr1];

    // ctx^T[d][s] += V^T · P
#pragma unroll
    for (int db = 0; db < 4; ++db) {
      const s16x8 v0 = *(const s16x8*)&vbuf[cur][(db * 16 + c) * 64 + rg0];
      const s16x8 v1 = *(const s16x8*)&vbuf[cur][(db * 16 + c) * 64 + rg1];
      co[db] = MFMA16(v0, pb0, co[db]);
      co[db] = MFMA16(v1, pb1, co[db]);
    }

    storeKV(cur ^ 1, cur ^ 1);   // tile it+1 -> buf[(it+1)&1]
  }

  // final l reduction across quads (lanes c, c+16, c+32, c+48 share s)
  float rs = l_lane;
  rs += __shfl_xor(rs, 16);
  rs += __shfl_xor(rs, 32);
  const float invl = 1.f / rs;

  const int hh = bh % NHEAD;
  const long tok = (long)(bh / NHEAD) * S_LEN + qs0 + w * 16 + c;
#pragma unroll
  for (int db = 0; db < 4; ++db) {
    uint2 ov;
    ov.x = pk_bf16(co[db][0] * invl, co[db][1] * invl);
    ov.y = pk_bf16(co[db][2] * invl, co[db][3] * invl);
    *(uint2*)(Ctx + tok * DMODEL + hh * 64 + db * 16 + g * 4) = ov;
  }
}

// ---------------------------------------------------------------------------
extern "C" void kernel_launch(void* const* d_in, const int* in_sizes, int n_in,
                              void* d_out, int out_size, void* d_ws, size_t ws_size,
                              hipStream_t stream) {
  const float* q   = (const float*)d_in[0];
  const float* k   = (const float*)d_in[1];
  const float* v   = (const float*)d_in[2];
  const float* w_q = (const float*)d_in[3];
  const float* b_q = (const float*)d_in[4];
  const float* w_k = (const float*)d_in[5];
  const float* b_k = (const float*)d_in[6];
  const float* w_v = (const float*)d_in[7];
  const float* b_v = (const float*)d_in[8];
  const float* w_o = (const float*)d_in[9];
  const float* b_o = (const float*)d_in[10];
  float* out = (float*)d_out;

  const long NELEM = (long)2 * NHEAD * S_LEN * 64;  // 3,145,728
  const long WELEM = (long)DMODEL * DMODEL;         // 589,824
  short* qh  = (short*)d_ws;
  short* kh  = qh + NELEM;
  short* vt  = kh + NELEM;
  short* ctx = vt + NELEM;
  short* wqb = ctx + NELEM;
  short* wkb = wqb + WELEM;
  short* wvb = wkb + WELEM;
  short* wob = wvb + WELEM;

  dim3 blk(256);
  convert_w<<<dim3(576, 4), blk, 0, stream>>>(w_q, w_k, w_v, w_o,
                                              wqb, wkb, wvb, wob);
  qkv_kernel<<<dim3(1152), blk, 0, stream>>>(q, k, v, wqb, wkb, wvb,
                                             b_q, b_k, b_v, qh, kh, vt);
  attn_kernel<<<dim3(32, 24), blk, 0, stream>>>(qh, kh, vt, ctx);
  o_kernel<<<dim3(384), blk, 0, stream>>>(ctx, wob, b_o, out);
}

// Round 8
// 204.368 us; speedup vs baseline: 2.4155x; 2.4155x over previous
//
#include <hip/hip_runtime.h>
#include <cstdint>

// MultiHeadAttention: B=2 S=2048 D=768 H=12 dk=64, fp32 in/out, bf16 MFMA inside.
//
//   convert : w_q,w_k,w_v,w_o fp32 -> bf16                        (ws)
//   qkv     : z=0 Qh[b][h][s][64] = (q @ w_q^T + b_q)*(log2e/8)   (bf16, ws)
//             z=1 Kh[b][h][s][64] =  k @ w_k^T + b_k              (bf16, ws)
//             z=2 Vt[b][h][64][t] = (v @ w_v^T + b_v)^T           (bf16, ws)
//   attn    : ctx[tok][768]   = flash attention (no-max softmax)  (bf16, ws)
//   oproj   : out[tok][768]   = ctx @ w_o^T + b_o                 (fp32, d_out)
//
// Pipelining: depth-2 register prefetch, double-buffered LDS, one barrier per
// tile, fetch issued right AFTER the barrier. All pipeline register sets are
// NAMED (A/B) with compile-time indices -- runtime-indexed register arrays
// get demoted to scratch (round-7: 448 MB scratch writes, 4x regression).

#define S_LEN 2048
#define NHEAD 12
#define DMODEL 768

typedef short s16x8 __attribute__((ext_vector_type(8)));
typedef float f32x4 __attribute__((ext_vector_type(4)));

#define MFMA16(a, b, c) __builtin_amdgcn_mfma_f32_16x16x32_bf16((a), (b), (c), 0, 0, 0)

__device__ __forceinline__ unsigned int pk_bf16(float a, float b) {
  unsigned int ua = __float_as_uint(a), ub = __float_as_uint(b);
  ua = (ua + 0x7FFFu + ((ua >> 16) & 1u)) >> 16;   // RNE
  ub = (ub + 0x7FFFu + ((ub >> 16) & 1u)) >> 16;
  return ua | (ub << 16);
}
__device__ __forceinline__ short bf16r(float a) {
  unsigned int ua = __float_as_uint(a);
  return (short)((ua + 0x7FFFu + ((ua >> 16) & 1u)) >> 16);
}
// pack hi16(b)<<16 | hi16(a) in ONE v_perm_b32 (trunc; bias cancelled via l)
__device__ __forceinline__ unsigned int pk_trunc(float a, float b) {
  return __builtin_amdgcn_perm(__float_as_uint(b), __float_as_uint(a), 0x07060302u);
}
__device__ __forceinline__ float bf16_floor(float a) {
  return __uint_as_float(__float_as_uint(a) & 0xFFFF0000u);
}

// ---------------------------------------------------------------------------
// Weight fp32 -> bf16 convert. grid (576, 4) x 256 threads, float4/thread.
// ---------------------------------------------------------------------------
__global__ __launch_bounds__(256)
void convert_w(const float* __restrict__ w0, const float* __restrict__ w1,
               const float* __restrict__ w2, const float* __restrict__ w3,
               short* __restrict__ o0, short* __restrict__ o1,
               short* __restrict__ o2, short* __restrict__ o3) {
  const float* src = (blockIdx.y == 0) ? w0 : (blockIdx.y == 1) ? w1
                   : (blockIdx.y == 2) ? w2 : w3;
  short* dst = (blockIdx.y == 0) ? o0 : (blockIdx.y == 1) ? o1
             : (blockIdx.y == 2) ? o2 : o3;
  const long i = ((long)blockIdx.x * 256 + threadIdx.x) * 4;
  float4 f = *(const float4*)(src + i);
  uint2 u;
  u.x = pk_bf16(f.x, f.y);
  u.y = pk_bf16(f.z, f.w);
  *(uint2*)(dst + i) = u;
}

// ---------------------------------------------------------------------------
// 64x128 GEMM body. C[m][n] = sum_k A[m][k]*B[n][k], K=768, BK=32, NIT=24.
// 4 waves, wave tile 32m x 64n. LDS 30 KB -> 5 blocks/CU.
// 2x-unrolled pipeline, named register sets A/B, explicit buf0/buf1:
//   even tile 2j: barrier; fetchA(2j+2); compute(buf0); storeB->buf1
//   odd  tile 2j+1: barrier; fetchB(2j+3); compute(buf1); storeA->buf0
// ---------------------------------------------------------------------------
template <bool ABF>
__device__ __forceinline__ void gemm64x128db(const void* __restrict__ Av,
                                             const short* __restrict__ Bv,
                                             int m0, int n0, f32x4 (&acc)[2][4],
                                             short* Alds, short* Blds) {
  constexpr int K = 768;
  constexpr int NIT = K / 32;          // 24 (even)
  const int tid  = threadIdx.x;
  const int lane = tid & 63;
  const int w    = tid >> 6;
  const int g    = lane >> 4;
  const int c    = lane & 15;
  const int wm   = (w & 1) * 32;
  const int wn   = (w >> 1) * 64;
  const int ar   = tid >> 2, ac = (tid & 3) * 8;    // A 64x32: 8 shorts/thr
  const int br   = tid >> 1, bc = (tid & 1) * 16;   // B 128x32: 16 shorts/thr

#pragma unroll
  for (int i = 0; i < 2; ++i)
#pragma unroll
    for (int j = 0; j < 4; ++j) acc[i][j] = (f32x4){0.f, 0.f, 0.f, 0.f};

  short* A0 = Alds;            short* B0 = Blds;
  short* A1 = Alds + 64 * 40;  short* B1 = Blds + 128 * 40;

  // named prefetch sets (all compile-time indexed)
  float4 rafA0, rafA1, rafB0, rafB1;   // fp32 A path
  uint4  rabA, rabB;                   // bf16 A path
  uint4  rbA0, rbA1, rbB0, rbB1;

  auto fetchA = [&](int kt) {
    if (ABF) {
      rabA = *(const uint4*)((const short*)Av + (long)(m0 + ar) * K + kt + ac);
    } else {
      const float* Ap = (const float*)Av + (long)(m0 + ar) * K + kt + ac;
      rafA0 = ((const float4*)Ap)[0];
      rafA1 = ((const float4*)Ap)[1];
    }
    const short* Bp = Bv + (long)(n0 + br) * K + kt + bc;
    rbA0 = *(const uint4*)Bp;
    rbA1 = *(const uint4*)(Bp + 8);
  };
  auto fetchB = [&](int kt) {
    if (ABF) {
      rabB = *(const uint4*)((const short*)Av + (long)(m0 + ar) * K + kt + ac);
    } else {
      const float* Ap = (const float*)Av + (long)(m0 + ar) * K + kt + ac;
      rafB0 = ((const float4*)Ap)[0];
      rafB1 = ((const float4*)Ap)[1];
    }
    const short* Bp = Bv + (long)(n0 + br) * K + kt + bc;
    rbB0 = *(const uint4*)Bp;
    rbB1 = *(const uint4*)(Bp + 8);
  };
  auto storeA = [&](short* Ab, short* Bb) {
    if (ABF) {
      *(uint4*)&Ab[ar * 40 + ac] = rabA;
    } else {
      uint4 u;
      u.x = pk_bf16(rafA0.x, rafA0.y); u.y = pk_bf16(rafA0.z, rafA0.w);
      u.z = pk_bf16(rafA1.x, rafA1.y); u.w = pk_bf16(rafA1.z, rafA1.w);
      *(uint4*)&Ab[ar * 40 + ac] = u;
    }
    *(uint4*)&Bb[br * 40 + bc]     = rbA0;
    *(uint4*)&Bb[br * 40 + bc + 8] = rbA1;
  };
  auto storeB = [&](short* Ab, short* Bb) {
    if (ABF) {
      *(uint4*)&Ab[ar * 40 + ac] = rabB;
    } else {
      uint4 u;
      u.x = pk_bf16(rafB0.x, rafB0.y); u.y = pk_bf16(rafB0.z, rafB0.w);
      u.z = pk_bf16(rafB1.x, rafB1.y); u.w = pk_bf16(rafB1.z, rafB1.w);
      *(uint4*)&Ab[ar * 40 + ac] = u;
    }
    *(uint4*)&Bb[br * 40 + bc]     = rbB0;
    *(uint4*)&Bb[br * 40 + bc + 8] = rbB1;
  };
  auto compute = [&](const short* Ab, const short* Bb) {
    s16x8 af[2], bf[4];
#pragma unroll
    for (int mb = 0; mb < 2; ++mb)
      af[mb] = *(const s16x8*)&Ab[(wm + mb * 16 + c) * 40 + g * 8];
#pragma unroll
    for (int nb = 0; nb < 4; ++nb)
      bf[nb] = *(const s16x8*)&Bb[(wn + nb * 16 + c) * 40 + g * 8];
#pragma unroll
    for (int mb = 0; mb < 2; ++mb)
#pragma unroll
      for (int nb = 0; nb < 4; ++nb)
        acc[mb][nb] = MFMA16(af[mb], bf[nb], acc[mb][nb]);
  };

  fetchA(0);            // tile 0
  fetchB(32);           // tile 1 (in flight while tile 0 stores)
  storeA(A0, B0);       // buf0 = tile 0
  for (int j = 0; j < NIT / 2; ++j) {
    __syncthreads();                                  // buf0 (tile 2j) visible
    fetchA((2 * j + 2 < NIT) ? (2 * j + 2) * 32 : 0); // tile 2j+2 -> set A
    compute(A0, B0);
    storeB(A1, B1);                                   // tile 2j+1 -> buf1
    __syncthreads();                                  // buf1 visible
    fetchB((2 * j + 3 < NIT) ? (2 * j + 3) * 32 : 0); // tile 2j+3 -> set B
    compute(A1, B1);
    storeA(A0, B0);                                   // tile 2j+2 -> buf0
  }
}

// ---------------------------------------------------------------------------
// Fused QKV projection. 1152 blocks, XCD-swizzled: xcd = L&7 owns whole
// (m,z) A-tiles; the 6 n-siblings of an A-tile are consecutive on that XCD.
// ---------------------------------------------------------------------------
__global__ __launch_bounds__(256)
void qkv_kernel(const float* __restrict__ q, const float* __restrict__ k,
                const float* __restrict__ v,
                const short* __restrict__ wq, const short* __restrict__ wk,
                const short* __restrict__ wv,
                const float* __restrict__ bq, const float* __restrict__ bk,
                const float* __restrict__ bv,
                short* __restrict__ qh, short* __restrict__ kh,
                short* __restrict__ vt) {
  __shared__ short Alds[2 * 64 * 40];
  __shared__ short Blds[2 * 128 * 40];

  const int L   = blockIdx.x;        // 0..1151
  const int xcd = L & 7;
  const int i   = L >> 3;            // 0..143
  const int nt  = i % 6;
  const int pl  = xcd * 24 + i / 6;  // 0..191 (m,z) pair
  const int z   = pl >> 6;
  const int mt  = pl & 63;
  const int m0  = mt * 64;           // token
  const int n0  = nt * 128;          // feature

  const float* A = (z == 0) ? q : (z == 1) ? k : v;
  const short* B = (z == 0) ? wq : (z == 1) ? wk : wv;
  const float* bias = (z == 0) ? bq : (z == 1) ? bk : bv;

  f32x4 acc[2][4];
  gemm64x128db<false>(A, B, m0, n0, acc, Alds, Blds);

  const int lane = threadIdx.x & 63, w = threadIdx.x >> 6;
  const int g = lane >> 4, c = lane & 15;
  const int wm = (w & 1) * 32, wn = (w >> 1) * 64;

  if (z < 2) {
    short* outp = z ? kh : qh;
    const float scale = z ? 1.0f : 0.18033688011112042f;  // log2e/8
#pragma unroll
    for (int mb = 0; mb < 2; ++mb) {
#pragma unroll
      for (int nb = 0; nb < 4; ++nb) {
        const int n = n0 + wn + nb * 16 + c;
        const float bvv = bias[n];
        const int hh = n >> 6, d = n & 63;
#pragma unroll
        for (int r = 0; r < 4; ++r) {
          const int m = m0 + wm + mb * 16 + g * 4 + r;
          const int b = m >> 11, s = m & 2047;
          const float val = (acc[mb][nb][r] + bvv) * scale;
          outp[(((long)(b * NHEAD + hh) * S_LEN + s) << 6) + d] = bf16r(val);
        }
      }
    }
  } else {  // V: transposed write Vt[b][h][d][t], 4 consecutive t per lane
#pragma unroll
    for (int mb = 0; mb < 2; ++mb) {
#pragma unroll
      for (int nb = 0; nb < 4; ++nb) {
        const int n = n0 + wn + nb * 16 + c;   // feature
        const float bvv = bias[n];
        const int hh = n >> 6, d = n & 63;
        const int m_base = m0 + wm + mb * 16 + g * 4;   // token base
        const int b = m_base >> 11, t = m_base & 2047;
        uint2 ov;
        ov.x = pk_bf16(acc[mb][nb][0] + bvv, acc[mb][nb][1] + bvv);
        ov.y = pk_bf16(acc[mb][nb][2] + bvv, acc[mb][nb][3] + bvv);
        *(uint2*)(vt + ((long)(b * NHEAD + hh) * 64 + d) * S_LEN + t) = ov;
      }
    }
  }
}

// ---------------------------------------------------------------------------
// Output projection. A = ctx (bf16), B = w_o (bf16), out fp32.
// 384 blocks, XCD-swizzled: xcd owns 8 m-tiles (6 n-siblings consecutive).
// ---------------------------------------------------------------------------
__global__ __launch_bounds__(256)
void o_kernel(const short* __restrict__ ctx, const short* __restrict__ wo,
              const float* __restrict__ bo, float* __restrict__ out) {
  __shared__ short Alds[2 * 64 * 40];
  __shared__ short Blds[2 * 128 * 40];

  const int L   = blockIdx.x;        // 0..383
  const int xcd = L & 7;
  const int i   = L >> 3;            // 0..47
  const int nt  = i % 6;
  const int mt  = xcd * 8 + i / 6;   // 0..63
  const int m0  = mt * 64;
  const int n0  = nt * 128;

  f32x4 acc[2][4];
  gemm64x128db<true>(ctx, wo, m0, n0, acc, Alds, Blds);

  const int lane = threadIdx.x & 63, w = threadIdx.x >> 6;
  const int g = lane >> 4, c = lane & 15;
  const int wm = (w & 1) * 32, wn = (w >> 1) * 64;
#pragma unroll
  for (int mb = 0; mb < 2; ++mb) {
#pragma unroll
    for (int nb = 0; nb < 4; ++nb) {
      const int n = n0 + wn + nb * 16 + c;
      const float bvv = bo[n];
#pragma unroll
      for (int r = 0; r < 4; ++r) {
        const int m = m0 + wm + mb * 16 + g * 4 + r;
        out[(long)m * DMODEL + n] = acc[mb][nb][r] + bvv;
      }
    }
  }
}

// ---------------------------------------------------------------------------
// Flash attention, no-max softmax. Same named-set A/B, 2x-unrolled pipeline.
// S^T = K·Q^T per 64-key tile; softmax rows at lane&15; per-lane l partials.
// kbuf/vbuf XOR-swizzled at 16B granules; pbuf stride 64 + XOR swizzle.
// LDS total 40960 B = 4 blocks/CU.
// ---------------------------------------------------------------------------
__global__ __launch_bounds__(256)
void attn_kernel(const short* __restrict__ Qh, const short* __restrict__ Kh,
                 const short* __restrict__ Vt, short* __restrict__ Ctx) {
  __shared__ short kbuf[2][64 * 64];      // swizzled [t][d]
  __shared__ short vbuf[2][64 * 64];      // swizzled [d][t]
  __shared__ short pbuf[4][16 * 64];      // per-wave [s][t], XOR-swizzled

  const int tid  = threadIdx.x;
  const int lane = tid & 63;
  const int w    = tid >> 6;
  const int g    = lane >> 4;
  const int c    = lane & 15;
  const int bh   = blockIdx.y;            // 0..23
  const int qs0  = blockIdx.x * 64;
  const long base = (long)bh * S_LEN * 64;
  const short* Qb = Qh + base;
  const short* Kb = Kh + base;
  const short* Vb = Vt + base;

  // Q fragments (B operand): n=s=lane&15, k=d=quad*8+j (+32*kb)
  const long qrow = (long)(qs0 + w * 16 + c) * 64;
  const s16x8 qf0 = *(const s16x8*)(Qb + qrow + g * 8);
  const s16x8 qf1 = *(const s16x8*)(Qb + qrow + 32 + g * 8);

  f32x4 co[4];
#pragma unroll
  for (int i = 0; i < 4; ++i) co[i] = (f32x4){0.f, 0.f, 0.f, 0.f};
  float l_lane = 0.f;

  const int srow = tid >> 2;           // 0..63
  const int sq   = tid & 3;
  const int sw   = srow & 7;
  const int sg0  = ((2 * sq)     ^ sw) * 8;
  const int sg1  = ((2 * sq + 1) ^ sw) * 8;
  const int cw   = c & 7;
  const int rg0  = ((g)     ^ cw) * 8;
  const int rg1  = ((4 + g) ^ cw) * 8;

  const short* kg = Kb + (long)srow * 64 + sq * 16;     // + row*64
  const short* vg = Vb + (long)srow * S_LEN + sq * 16;  // + t

  // named prefetch sets
  uint4 rkA0, rkA1, rvA0, rvA1;
  uint4 rkB0, rkB1, rvB0, rvB1;
  auto fetchA = [&](long t0) {    // t0 = starting row/t (tile*64)
    rkA0 = *(const uint4*)(kg + t0 * 64);
    rkA1 = *(const uint4*)(kg + t0 * 64 + 8);
    rvA0 = *(const uint4*)(vg + t0);
    rvA1 = *(const uint4*)(vg + t0 + 8);
  };
  auto fetchB = [&](long t0) {
    rkB0 = *(const uint4*)(kg + t0 * 64);
    rkB1 = *(const uint4*)(kg + t0 * 64 + 8);
    rvB0 = *(const uint4*)(vg + t0);
    rvB1 = *(const uint4*)(vg + t0 + 8);
  };
  auto storeA = [&](short* kb2, short* vb2) {
    *(uint4*)&kb2[srow * 64 + sg0] = rkA0;
    *(uint4*)&kb2[srow * 64 + sg1] = rkA1;
    *(uint4*)&vb2[srow * 64 + sg0] = rvA0;
    *(uint4*)&vb2[srow * 64 + sg1] = rvA1;
  };
  auto storeB = [&](short* kb2, short* vb2) {
    *(uint4*)&kb2[srow * 64 + sg0] = rkB0;
    *(uint4*)&kb2[srow * 64 + sg1] = rkB1;
    *(uint4*)&vb2[srow * 64 + sg0] = rvB0;
    *(uint4*)&vb2[srow * 64 + sg1] = rvB1;
  };

  // pbuf swizzled offsets (stride 64 shorts, 16B granules XOR (c&7))
  const int pr0 = c * 64 + ((g ^ cw) * 8);
  const int pr1 = c * 64 + (((4 + g) ^ cw) * 8);

  auto step = [&](const short* kb2, const short* vb2) {
    // S^T[t][s]: A = K (m=t), B = Q (n=s)
    f32x4 st[4];
#pragma unroll
    for (int mb = 0; mb < 4; ++mb) {
      const s16x8 k0 = *(const s16x8*)&kb2[(mb * 16 + c) * 64 + rg0];
      const s16x8 k1 = *(const s16x8*)&kb2[(mb * 16 + c) * 64 + rg1];
      f32x4 z = (f32x4){0.f, 0.f, 0.f, 0.f};
      z = MFMA16(k0, qf0, z);
      z = MFMA16(k1, qf1, z);
      st[mb] = z;
    }
    // P = exp2(S'); l from TRUNCATED values; pack via v_perm
#pragma unroll
    for (int mb = 0; mb < 4; ++mb) {
      float p0 = __builtin_amdgcn_exp2f(st[mb][0]);
      float p1 = __builtin_amdgcn_exp2f(st[mb][1]);
      float p2 = __builtin_amdgcn_exp2f(st[mb][2]);
      float p3 = __builtin_amdgcn_exp2f(st[mb][3]);
      l_lane += bf16_floor(p0) + bf16_floor(p1) + bf16_floor(p2) + bf16_floor(p3);
      uint2 pw;
      pw.x = pk_trunc(p0, p1);
      pw.y = pk_trunc(p2, p3);
      const int pg = ((2 * mb + (g >> 1)) ^ cw) * 8 + (g & 1) * 4;
      *(uint2*)&pbuf[w][c * 64 + pg] = pw;
    }
    const s16x8 pb0 = *(const s16x8*)&pbuf[w][pr0];
    const s16x8 pb1 = *(const s16x8*)&pbuf[w][pr1];
    // ctx^T[d][s] += V^T · P
#pragma unroll
    for (int db = 0; db < 4; ++db) {
      const s16x8 v0 = *(const s16x8*)&vb2[(db * 16 + c) * 64 + rg0];
      const s16x8 v1 = *(const s16x8*)&vb2[(db * 16 + c) * 64 + rg1];
      co[db] = MFMA16(v0, pb0, co[db]);
      co[db] = MFMA16(v1, pb1, co[db]);
    }
  };

  constexpr int NT = S_LEN / 64;   // 32 tiles
  fetchA(0);
  fetchB(64);
  storeA(kbuf[0], vbuf[0]);
  for (int j = 0; j < NT / 2; ++j) {
    __syncthreads();                                        // buf0 (tile 2j)
    fetchA((2 * j + 2 < NT) ? (long)(2 * j + 2) * 64 : 0);  // tile 2j+2 -> A
    step(kbuf[0], vbuf[0]);
    storeB(kbuf[1], vbuf[1]);                               // tile 2j+1 -> buf1
    __syncthreads();                                        // buf1 visible
    fetchB((2 * j + 3 < NT) ? (long)(2 * j + 3) * 64 : 0);  // tile 2j+3 -> B
    step(kbuf[1], vbuf[1]);
    storeA(kbuf[0], vbuf[0]);                               // tile 2j+2 -> buf0
  }

  // final l reduction across quads (lanes c, c+16, c+32, c+48 share s)
  float rs = l_lane;
  rs += __shfl_xor(rs, 16);
  rs += __shfl_xor(rs, 32);
  const float invl = 1.f / rs;

  const int hh = bh % NHEAD;
  const long tok = (long)(bh / NHEAD) * S_LEN + qs0 + w * 16 + c;
#pragma unroll
  for (int db = 0; db < 4; ++db) {
    uint2 ov;
    ov.x = pk_bf16(co[db][0] * invl, co[db][1] * invl);
    ov.y = pk_bf16(co[db][2] * invl, co[db][3] * invl);
    *(uint2*)(Ctx + tok * DMODEL + hh * 64 + db * 16 + g * 4) = ov;
  }
}

// ---------------------------------------------------------------------------
extern "C" void kernel_launch(void* const* d_in, const int* in_sizes, int n_in,
                              void* d_out, int out_size, void* d_ws, size_t ws_size,
                              hipStream_t stream) {
  const float* q   = (const float*)d_in[0];
  const float* k   = (const float*)d_in[1];
  const float* v   = (const float*)d_in[2];
  const float* w_q = (const float*)d_in[3];
  const float* b_q = (const float*)d_in[4];
  const float* w_k = (const float*)d_in[5];
  const float* b_k = (const float*)d_in[6];
  const float* w_v = (const float*)d_in[7];
  const float* b_v = (const float*)d_in[8];
  const float* w_o = (const float*)d_in[9];
  const float* b_o = (const float*)d_in[10];
  float* out = (float*)d_out;

  const long NELEM = (long)2 * NHEAD * S_LEN * 64;  // 3,145,728
  const long WELEM = (long)DMODEL * DMODEL;         // 589,824
  short* qh  = (short*)d_ws;
  short* kh  = qh + NELEM;
  short* vt  = kh + NELEM;
  short* ctx = vt + NELEM;
  short* wqb = ctx + NELEM;
  short* wkb = wqb + WELEM;
  short* wvb = wkb + WELEM;
  short* wob = wvb + WELEM;

  dim3 blk(256);
  convert_w<<<dim3(576, 4), blk, 0, stream>>>(w_q, w_k, w_v, w_o,
                                              wqb, wkb, wvb, wob);
  qkv_kernel<<<dim3(1152), blk, 0, stream>>>(q, k, v, wqb, wkb, wvb,
                                             b_q, b_k, b_v, qh, kh, vt);
  attn_kernel<<<dim3(32, 24), blk, 0, stream>>>(qh, kh, vt, ctx);
  o_kernel<<<dim3(384), blk, 0, stream>>>(ctx, wob, b_o, out);
}